// Round 5
// baseline (2444.850 us; speedup 1.0000x reference)
//
#include <hip/hip_runtime.h>
#include <cstdint>
#include <cstddef>

// Problem constants
#define TT 8
#define NN 20000
#define FIN 128
#define HH 128
#define NHEADS 4
#define DD 32
#define RR 12
#define EE 40000
#define LL 2
#define CC 16
#define RN (RR*NN)        // 240000 segments (relation, dst-node)
#define RE (RR*EE)        // 480000 edges total
#define TNH ((size_t)TT*NN*HH)   // 20.48M floats per type-space tensor

struct Job { const float* in; const float* w; const float* b; float* out; };
struct Jobs8  { Job j[8]; };
struct Jobs16 { Job j[16]; };

// ---------------------------------------------------------------------------
// zero fill (avoids hipMemsetAsync in the capture path)
// ---------------------------------------------------------------------------
__global__ __launch_bounds__(256) void zero_kernel(float4* __restrict__ p, int n4) {
    int i = blockIdx.x * 256 + threadIdx.x;
    int stride = gridDim.x * 256;
    for (; i < n4; i += stride) p[i] = make_float4(0.f, 0.f, 0.f, 0.f);
}

// ---------------------------------------------------------------------------
// CSR build: histogram -> scan -> scatter (keyed by r*N + edge_dst)
// ---------------------------------------------------------------------------
__global__ __launch_bounds__(256) void hist_kernel(const int* __restrict__ edge_dst,
                                                   int* __restrict__ cnt) {
    int g = blockIdx.x * 256 + threadIdx.x;
    if (g < RE) {
        int r = g / EE;
        atomicAdd(&cnt[r * NN + edge_dst[g]], 1);
    }
}

__global__ __launch_bounds__(256) void scan_local(const int* __restrict__ in,
                                                  int* __restrict__ out,
                                                  int* __restrict__ bsum, int n) {
    __shared__ int sh[256];
    int t = threadIdx.x;
    int base = blockIdx.x * 1024 + t * 4;
    int v0 = (base + 0 < n) ? in[base + 0] : 0;
    int v1 = (base + 1 < n) ? in[base + 1] : 0;
    int v2 = (base + 2 < n) ? in[base + 2] : 0;
    int v3 = (base + 3 < n) ? in[base + 3] : 0;
    int s = v0 + v1 + v2 + v3;
    sh[t] = s;
    __syncthreads();
    for (int off = 1; off < 256; off <<= 1) {
        int tmp = (t >= off) ? sh[t - off] : 0;
        __syncthreads();
        sh[t] += tmp;
        __syncthreads();
    }
    int incl = sh[t];
    int e = incl - s;                 // exclusive prefix of this thread's chunk
    if (t == 255) bsum[blockIdx.x] = incl;
    if (base + 0 < n) out[base + 0] = e; e += v0;
    if (base + 1 < n) out[base + 1] = e; e += v1;
    if (base + 2 < n) out[base + 2] = e; e += v2;
    if (base + 3 < n) out[base + 3] = e;
}

__global__ __launch_bounds__(256) void scan_bsum(int* __restrict__ bsum, int nb) {
    __shared__ int sh[256];
    int t = threadIdx.x;
    int v = (t < nb) ? bsum[t] : 0;
    sh[t] = v;
    __syncthreads();
    for (int off = 1; off < 256; off <<= 1) {
        int tmp = (t >= off) ? sh[t - off] : 0;
        __syncthreads();
        sh[t] += tmp;
        __syncthreads();
    }
    if (t < nb) bsum[t] = sh[t] - v;  // exclusive
}

// adds block prefix; writes both ofs and cursor (replaces the d2d memcpy)
__global__ __launch_bounds__(256) void scan_add(int* __restrict__ ofs,
                                                int* __restrict__ cursor,
                                                const int* __restrict__ bsum, int n) {
    int i = blockIdx.x * 256 + threadIdx.x;
    if (i < n) {
        int v = ofs[i] + bsum[i >> 10];
        ofs[i] = v;
        cursor[i] = v;
    }
}

__global__ __launch_bounds__(256) void scatter_kernel(const int* __restrict__ edge_dst,
                                                      int* __restrict__ cursor,
                                                      int* __restrict__ eidx) {
    int g = blockIdx.x * 256 + threadIdx.x;
    if (g < RE) {
        int r = g / EE;
        int pos = atomicAdd(&cursor[r * NN + edge_dst[g]], 1);
        eidx[pos] = g;
    }
}

// ---------------------------------------------------------------------------
// Generic 128-col GEMM, K=128, tile 128 rows x 128 cols, BK=32, 256 threads.
// ACT: 0 = none (+bias)
//      1 = relu(acc+bias)
//      2 = gelu applied to the INPUT during staging; out = beta*(acc+b)+(1-beta)*out_prev
// Jobs passed BY VALUE (kernarg) — no device-side job table.
// ---------------------------------------------------------------------------
template<int ACT, typename JT>
__global__ __launch_bounds__(256) void gemm128(const JT jt,
                                               const float* __restrict__ skip_l) {
    __shared__ float lw[32][128];   // W chunk [k][g]
    __shared__ float li[32][132];   // in chunk transposed [k][row]; rows 16B-aligned
    const Job jb = jt.j[blockIdx.y];
    const int tid = threadIdx.x;
    const int row0 = blockIdx.x * 128;
    const int col = (tid & 31) * 4;        // 0..124
    const int rbase = (tid >> 5) * 16;     // 0..112
    float4 acc[16];
    #pragma unroll
    for (int i = 0; i < 16; i++) acc[i] = make_float4(0.f, 0.f, 0.f, 0.f);
    const float4 bb = *(const float4*)(jb.b + col);

    for (int k0 = 0; k0 < 128; k0 += 32) {
        #pragma unroll
        for (int it = 0; it < 4; ++it) {          // stage W 32x128
            int idx = tid + it * 256;
            int kk = idx >> 5;
            int c4 = (idx & 31) * 4;
            *(float4*)&lw[kk][c4] = *(const float4*)(jb.w + (k0 + kk) * 128 + c4);
        }
        #pragma unroll
        for (int p = 0; p < 4; ++p) {             // stage in 128x32 transposed
            int rr = (tid >> 3) + p * 32;
            int kk4 = (tid & 7) * 4;
            int rg = row0 + rr; if (rg >= NN) rg = NN - 1;
            float4 v = *(const float4*)(jb.in + (size_t)rg * 128 + k0 + kk4);
            if (ACT == 2) {   // exact gelu on input element
                v.x = 0.5f * v.x * (1.f + erff(v.x * 0.70710678118654752f));
                v.y = 0.5f * v.y * (1.f + erff(v.y * 0.70710678118654752f));
                v.z = 0.5f * v.z * (1.f + erff(v.z * 0.70710678118654752f));
                v.w = 0.5f * v.w * (1.f + erff(v.w * 0.70710678118654752f));
            }
            li[kk4 + 0][rr] = v.x; li[kk4 + 1][rr] = v.y;
            li[kk4 + 2][rr] = v.z; li[kk4 + 3][rr] = v.w;
        }
        __syncthreads();
        #pragma unroll 4
        for (int kk = 0; kk < 32; kk++) {
            const float4 bv = *(const float4*)&lw[kk][col];
            #pragma unroll
            for (int i4 = 0; i4 < 4; i4++) {
                float4 a4 = *(const float4*)&li[kk][rbase + 4 * i4];
                float4& A0 = acc[4 * i4 + 0];
                float4& A1 = acc[4 * i4 + 1];
                float4& A2 = acc[4 * i4 + 2];
                float4& A3 = acc[4 * i4 + 3];
                A0.x += a4.x * bv.x; A0.y += a4.x * bv.y; A0.z += a4.x * bv.z; A0.w += a4.x * bv.w;
                A1.x += a4.y * bv.x; A1.y += a4.y * bv.y; A1.z += a4.y * bv.z; A1.w += a4.y * bv.w;
                A2.x += a4.z * bv.x; A2.y += a4.z * bv.y; A2.z += a4.z * bv.z; A2.w += a4.z * bv.w;
                A3.x += a4.w * bv.x; A3.y += a4.w * bv.y; A3.z += a4.w * bv.z; A3.w += a4.w * bv.w;
            }
        }
        __syncthreads();
    }
    float beta = 0.f;
    if (ACT == 2) beta = 1.f / (1.f + __expf(-skip_l[blockIdx.y]));
    #pragma unroll
    for (int i = 0; i < 16; i++) {
        int rg = row0 + rbase + i;
        if (rg < NN) {
            float4 o = acc[i];
            o.x += bb.x; o.y += bb.y; o.z += bb.z; o.w += bb.w;
            float* op = jb.out + (size_t)rg * 128 + col;
            if (ACT == 1) {
                o.x = fmaxf(o.x, 0.f); o.y = fmaxf(o.y, 0.f);
                o.z = fmaxf(o.z, 0.f); o.w = fmaxf(o.w, 0.f);
            }
            if (ACT == 2) {
                float4 hv = *(const float4*)op;
                o.x = beta * o.x + (1.f - beta) * hv.x;
                o.y = beta * o.y + (1.f - beta) * hv.y;
                o.z = beta * o.z + (1.f - beta) * hv.z;
                o.w = beta * o.w + (1.f - beta) * hv.w;
            }
            *(float4*)op = o;
        }
    }
}

// ---------------------------------------------------------------------------
// Pass 1: per-segment scores + online softmax stats.
//   qa[h,d]  = sum_e q[tdst,n,h,e] * a_rel[r,h,d,e]   (32-lane shfl rotation)
//   sc(edge) = (sum_d qa*k) * p[h]/sqrt(D)  -> alpha[g*4+h] (raw)
//   m,den per (seg,head) -> mbuf/dbuf
// 128 threads per segment (2 segments/block); head = lane/32.
// ---------------------------------------------------------------------------
__global__ __launch_bounds__(256) void score_kernel(
        const int* __restrict__ ofs, const int* __restrict__ cnt, const int* __restrict__ eidx,
        const int* __restrict__ edge_src,
        const int* __restrict__ rel_src, const int* __restrict__ rel_dst,
        const float* __restrict__ qb, const float* __restrict__ kb,
        const float* __restrict__ a_rel_l, const float* __restrict__ p_rel_l,
        float* __restrict__ alpha, float* __restrict__ mbuf, float* __restrict__ dbuf) {
    int grp = threadIdx.x >> 7;
    int lane = threadIdx.x & 127;
    int seg = blockIdx.x * 2 + grp;
    if (seg >= RN) return;
    int c = cnt[seg];
    if (c == 0) return;
    int r = seg / NN, n = seg - r * NN;
    int tsrc = rel_src[r], tdst = rel_dst[r];
    int hh = lane >> 5;
    int hsel = threadIdx.x & 32;        // head base lane within the 64-lane wave

    float qv = qb[((size_t)tdst * NN + n) * HH + lane];
    const float* Arow = a_rel_l + (((size_t)r * NHEADS + hh) * DD + (lane & 31)) * DD;
    float qa = 0.f;
    #pragma unroll
    for (int e = 0; e < 32; e += 4) {
        float4 a4 = *(const float4*)(Arow + e);
        qa += __shfl(qv, hsel + e + 0) * a4.x;
        qa += __shfl(qv, hsel + e + 1) * a4.y;
        qa += __shfl(qv, hsel + e + 2) * a4.z;
        qa += __shfl(qv, hsel + e + 3) * a4.w;
    }
    float pscale = p_rel_l[r * NHEADS + hh] * 0.17677669529663687f; // 1/sqrt(32)
    int base = ofs[seg];
    float m = -INFINITY, den = 0.f;
    for (int i = 0; i < c; i++) {
        int g = eidx[base + i];
        int src = edge_src[g];
        float kv = kb[((size_t)tsrc * NN + src) * HH + lane];
        float prod = qa * kv;
        prod += __shfl_xor(prod, 16);
        prod += __shfl_xor(prod, 8);
        prod += __shfl_xor(prod, 4);
        prod += __shfl_xor(prod, 2);
        prod += __shfl_xor(prod, 1);
        float sc = prod * pscale;
        float mn = fmaxf(m, sc);
        den = den * __expf(m - mn) + __expf(sc - mn);
        m = mn;
        if ((lane & 31) == 0) alpha[(size_t)g * NHEADS + hh] = sc;
    }
    if ((lane & 31) == 0) {
        mbuf[(size_t)seg * NHEADS + hh] = m;
        dbuf[(size_t)seg * NHEADS + hh] = den;
    }
}

// ---------------------------------------------------------------------------
// Pass 2: o_d = sum_e exp(sc-m)/den * v[tsrc,src,h,d]; rotate by m_rel; atomicAdd agg.
// ---------------------------------------------------------------------------
__global__ __launch_bounds__(256) void aggregate_kernel(
        const int* __restrict__ ofs, const int* __restrict__ cnt, const int* __restrict__ eidx,
        const int* __restrict__ edge_src,
        const int* __restrict__ rel_src, const int* __restrict__ rel_dst,
        const float* __restrict__ vb, const float* __restrict__ m_rel_l,
        const float* __restrict__ alpha, const float* __restrict__ mbuf,
        const float* __restrict__ dbuf, float* __restrict__ agg) {
    int grp = threadIdx.x >> 7;
    int lane = threadIdx.x & 127;
    int seg = blockIdx.x * 2 + grp;
    if (seg >= RN) return;
    int c = cnt[seg];
    if (c == 0) return;
    int r = seg / NN, n = seg - r * NN;
    int tsrc = rel_src[r], tdst = rel_dst[r];
    int hh = lane >> 5;
    int hsel = threadIdx.x & 32;

    float m = mbuf[(size_t)seg * NHEADS + hh];
    float inv = 1.f / dbuf[(size_t)seg * NHEADS + hh];
    int base = ofs[seg];
    float o = 0.f;
    for (int i = 0; i < c; i++) {
        int g = eidx[base + i];
        int src = edge_src[g];
        float sc = alpha[(size_t)g * NHEADS + hh];
        float a = __expf(sc - m) * inv;
        o += a * vb[((size_t)tsrc * NN + src) * HH + lane];
    }
    // out_e = sum_d o_d * M[h,d,e]; iteration d reads M[h][d][0..31] coalesced.
    const float* Mcol = m_rel_l + ((size_t)r * NHEADS + hh) * DD * DD + (lane & 31);
    float oe = 0.f;
    #pragma unroll 8
    for (int d = 0; d < 32; d++) {
        oe += __shfl(o, hsel + d) * Mcol[d * 32];
    }
    atomicAdd(&agg[((size_t)tdst * NN + n) * HH + lane], oe);
}

// ---------------------------------------------------------------------------
// Final classifier: out = h[0] @ Wout + bout   (N x 128) @ (128 x 16)
// ---------------------------------------------------------------------------
__global__ __launch_bounds__(256) void final_kernel(const float* __restrict__ h0,
        const float* __restrict__ Wout, const float* __restrict__ bout,
        float* __restrict__ out) {
    __shared__ float w[128 * 16];
    __shared__ float hs[16][132];
    for (int i = threadIdx.x; i < 128 * 16; i += 256) w[i] = Wout[i];
    int row0 = blockIdx.x * 16;
    for (int i = threadIdx.x; i < 16 * 128; i += 256) {
        int rr = i >> 7, kk = i & 127;
        int rg = row0 + rr; if (rg >= NN) rg = NN - 1;
        hs[rr][kk] = h0[(size_t)rg * 128 + kk];
    }
    __syncthreads();
    int rr = threadIdx.x >> 4, colc = threadIdx.x & 15;
    float s = bout[colc];
    #pragma unroll 8
    for (int k = 0; k < 128; k++) s += hs[rr][k] * w[k * 16 + colc];
    int rg = row0 + rr;
    if (rg < NN) out[(size_t)rg * 16 + colc] = s;
}

// ---------------------------------------------------------------------------
extern "C" void kernel_launch(void* const* d_in, const int* in_sizes, int n_in,
                              void* d_out, int out_size, void* d_ws, size_t ws_size,
                              hipStream_t stream) {
    const float* x        = (const float*)d_in[0];
    const int*   edge_src = (const int*)d_in[1];
    const int*   edge_dst = (const int*)d_in[2];
    const int*   rel_src  = (const int*)d_in[3];
    const int*   rel_dst  = (const int*)d_in[4];
    const float* Wenc     = (const float*)d_in[5];
    const float* benc     = (const float*)d_in[6];
    const float* Wk       = (const float*)d_in[7];
    const float* bk       = (const float*)d_in[8];
    const float* Wq       = (const float*)d_in[9];
    const float* bq       = (const float*)d_in[10];
    const float* Wv       = (const float*)d_in[11];
    const float* bv       = (const float*)d_in[12];
    const float* Wa       = (const float*)d_in[13];
    const float* ba       = (const float*)d_in[14];
    const float* skip     = (const float*)d_in[15];
    const float* a_rel    = (const float*)d_in[16];
    const float* m_rel    = (const float*)d_in[17];
    const float* p_rel    = (const float*)d_in[18];
    const float* Wout     = (const float*)d_in[19];
    const float* bout     = (const float*)d_in[20];
    float* out = (float*)d_out;
    float* wsf = (float*)d_ws;

    // workspace layout (floats):
    //   h     [TNH]                 persistent hidden state
    //   buf1  [TNH]                 q, then v
    //   buf2  [TNH]                 k, then agg
    //   alpha [RE*4], mbuf/dbuf [RN*4 each], CSR arrays
    const size_t NEED_FLOATS = 3 * TNH + (size_t)RE * NHEADS + 2 * (size_t)RN * NHEADS
                             + 3 * (size_t)RN + (size_t)RE + 256;
    if (ws_size < NEED_FLOATS * sizeof(float)) {
        // Workspace too small: degrade to a clean wrong-answer (diagnostic, no fault).
        zero_kernel<<<313, 256, 0, stream>>>((float4*)out, out_size / 4);
        return;
    }
    float* h    = wsf;
    float* buf1 = h    + TNH;
    float* buf2 = buf1 + TNH;
    float* alpha = buf2 + TNH;
    float* mbuf  = alpha + (size_t)RE * NHEADS;
    float* dbuf  = mbuf + (size_t)RN * NHEADS;
    int* cnt    = (int*)(dbuf + (size_t)RN * NHEADS);
    int* ofs    = cnt + RN;
    int* cursor = ofs + RN;
    int* eidx   = cursor + RN;
    int* bsum   = eidx + RE;

    const size_t NH = (size_t)NN * HH;
    const int RB = (NN + 127) / 128;   // 157 row blocks

    // ---- CSR build (shared by both layers) ----
    zero_kernel<<<235, 256, 0, stream>>>((float4*)cnt, RN / 4);
    hist_kernel<<<(RE + 255) / 256, 256, 0, stream>>>(edge_dst, cnt);
    int nb = (RN + 1023) / 1024;       // 235
    scan_local<<<nb, 256, 0, stream>>>(cnt, ofs, bsum, RN);
    scan_bsum<<<1, 256, 0, stream>>>(bsum, nb);
    scan_add<<<(RN + 255) / 256, 256, 0, stream>>>(ofs, cursor, bsum, RN);
    scatter_kernel<<<(RE + 255) / 256, 256, 0, stream>>>(edge_dst, cursor, eidx);

    // ---- encoder: h = relu(x @ Wenc + benc) ----
    {
        Jobs8 je;
        for (int t = 0; t < 8; t++)
            je.j[t] = { x + t * NH, Wenc + (size_t)t * 128 * 128, benc + t * 128, h + t * NH };
        gemm128<1, Jobs8><<<dim3(RB, 8), 256, 0, stream>>>(je, nullptr);
    }

    // ---- layers ----
    for (int l = 0; l < LL; l++) {
        // q -> buf1, k -> buf2
        Jobs16 jqk;
        for (int t = 0; t < 8; t++) {
            size_t wi = (size_t)(l * TT + t) * 128 * 128;
            size_t bi = (size_t)(l * TT + t) * 128;
            jqk.j[t]     = { h + t * NH, Wq + wi, bq + bi, buf1 + t * NH };
            jqk.j[8 + t] = { h + t * NH, Wk + wi, bk + bi, buf2 + t * NH };
        }
        gemm128<0, Jobs16><<<dim3(RB, 16), 256, 0, stream>>>(jqk, nullptr);

        // scores + softmax stats (reads q,k)
        score_kernel<<<RN / 2, 256, 0, stream>>>(ofs, cnt, eidx, edge_src,
                rel_src, rel_dst, buf1, buf2,
                a_rel + (size_t)l * RR * NHEADS * DD * DD,
                p_rel + (size_t)l * RR * NHEADS, alpha, mbuf, dbuf);

        // v -> buf1 (q dead)
        Jobs8 jv;
        for (int t = 0; t < 8; t++) {
            size_t wi = (size_t)(l * TT + t) * 128 * 128;
            size_t bi = (size_t)(l * TT + t) * 128;
            jv.j[t] = { h + t * NH, Wv + wi, bv + bi, buf1 + t * NH };
        }
        gemm128<0, Jobs8><<<dim3(RB, 8), 256, 0, stream>>>(jv, nullptr);

        // agg -> buf2 (k dead): zero then accumulate
        zero_kernel<<<2048, 256, 0, stream>>>((float4*)buf2, (int)(TNH / 4));
        aggregate_kernel<<<RN / 2, 256, 0, stream>>>(ofs, cnt, eidx, edge_src,
                rel_src, rel_dst, buf1,
                m_rel + (size_t)l * RR * NHEADS * DD * DD,
                alpha, mbuf, dbuf, buf2);

        // out-proj + skip blend (reads agg=buf2, blends into h)
        Jobs8 jo;
        for (int t = 0; t < 8; t++) {
            size_t wi = (size_t)(l * TT + t) * 128 * 128;
            size_t bi = (size_t)(l * TT + t) * 128;
            jo.j[t] = { buf2 + t * NH, Wa + wi, ba + bi, h + t * NH };
        }
        gemm128<2, Jobs8><<<dim3(RB, 8), 256, 0, stream>>>(jo, skip + l * TT);
    }

    // ---- classifier ----
    final_kernel<<<NN / 16, 256, 0, stream>>>(h, Wout, bout, out);
}